// Round 1
// baseline (282.618 us; speedup 1.0000x reference)
//
#include <hip/hip_runtime.h>

// CRF loss: sum_b(forward_score[b] - gold_score[b]).
// B=512, T=1024, L=32, SOS=0, END=1.
//
// Forward alg in exp-domain: q' = diag(exp(feat_t)) * E * q, E = exp(trans),
// with exact power-of-2 renorm every 4 steps (integer exponent accumulator C).
// forward = log(sum_j q_j * exp(trans[END,j])) + C*ln2.
//
// Mapping: 1 wave = 2 batches (lane = j + 32*h). Latency-bound sequential
// chain over T; per-step comm = LDS write + lgkm fence + 8 broadcast b128
// reads. Global feat/label prefetch ring depth 8 (vmcnt NOT drained by the
// lgkm-only fence). Gold score folded into the same loop (off-chain).

#define TT 1024
#define LL 32
#define BB 512

__device__ __forceinline__ void lds_fence() {
    // wait LDS ops only; leaves global prefetch (vmcnt) in flight
    asm volatile("s_waitcnt lgkmcnt(0)" ::: "memory");
}

__global__ __launch_bounds__(64, 1) void crf_forward_kernel(
    const float* __restrict__ emission,    // [B, T, L]
    const int*   __restrict__ label_ids,   // [B, T]
    const float* __restrict__ transitions, // [L, L]
    float*       __restrict__ diff_out)    // [B] forward - gold
{
    __shared__ __align__(16) float shT[LL * LL];   // raw transitions
    __shared__ __align__(16) float shQ[2][64];     // double-buffered q

    const int lane = threadIdx.x;       // 0..63
    const int j    = lane & 31;         // state index
    const int h    = lane >> 5;         // batch half
    const int b    = blockIdx.x * 2 + h;

    // ---- stage transitions into LDS (64 lanes x 4 float4 = 1024 floats) ----
    {
        const float4* g4 = (const float4*)transitions;
        float4* s4 = (float4*)shT;
#pragma unroll
        for (int m = 0; m < 4; ++m) s4[lane + 64 * m] = g4[lane + 64 * m];
    }
    lds_fence();
    __builtin_amdgcn_wave_barrier();

    // ---- per-lane E row: E[i] = exp(trans[j][i]) ----
    float E[32];
#pragma unroll
    for (int i = 0; i < 32; ++i) E[i] = __expf(shT[j * 32 + i]);
    const float Eend = __expf(shT[1 * 32 + j]);   // row END=1, col j

    const float* emB  = emission + (size_t)b * TT * LL + j;  // stride LL per t
    const int*   labB = label_ids + b * TT;

    // ---- prefetch ring depth 8 ----
    float ring[8];
    int   lring[8];
#pragma unroll
    for (int s = 0; s < 8; ++s) {
        ring[s]  = emB[s * LL];
        lring[s] = labB[s];
    }

    float q = (j == 0) ? 1.0f : 0.0f;   // exp(alpha0): one-hot at SOS
    int   C = 0;                        // log2 scale accumulator (exact)
    float emit_acc = 0.0f, trans_acc = 0.0f;
    int   prev = 0;                     // SOS

    float feat_cur = ring[0];
    float fexp_cur = __expf(feat_cur);
    int   lab_cur  = lring[0];

    for (int t0 = 0; t0 < TT; t0 += 8) {
#pragma unroll
        for (int s = 0; s < 8; ++s) {
            const int  t  = t0 + s;
            const int  par = s & 1;
            const bool RN = (s == 3) || (s == 7);   // renorm every 4 steps

            // publish q, gather all 32 q's of this half
            shQ[par][lane] = q;
            lds_fence();
            const float4* P4 = (const float4*)&shQ[par][h * 32];

            float a0 = 0.f, a1 = 0.f, a2 = 0.f, a3 = 0.f;
            float maxp = 0.f;
#pragma unroll
            for (int m = 0; m < 8; ++m) {
                float4 p = P4[m];
                a0 = fmaf(E[4 * m + 0], p.x, a0);
                a1 = fmaf(E[4 * m + 1], p.y, a1);
                a2 = fmaf(E[4 * m + 2], p.z, a2);
                a3 = fmaf(E[4 * m + 3], p.w, a3);
                if (RN) {
                    maxp = fmaxf(maxp, fmaxf(fmaxf(p.x, p.y), fmaxf(p.z, p.w)));
                }
            }
            float sdot = (a0 + a1) + (a2 + a3);
            float qn = sdot * fexp_cur;

            // ---- gold score (off critical path) ----
            emit_acc += (j == lab_cur) ? feat_cur : 0.0f;     // emission gather
            trans_acc += shT[lab_cur * 32 + prev];            // broadcast read
            prev = lab_cur;

            // ---- exact power-of-2 renorm ----
            if (RN) {
                int e = ((__float_as_int(maxp) >> 23) & 0xff) - 127;
                qn *= __int_as_float((127 - e) << 23);        // * 2^-e, exact
                C += e;
            }
            q = qn;

            // ---- prefetch t+8, prep next step's feat/label ----
            int tp = t + 8; if (tp > TT - 1) tp = TT - 1;
            ring[s]  = emB[tp * LL];
            lring[s] = labB[tp];
            feat_cur = ring[(s + 1) & 7];
            fexp_cur = __expf(feat_cur);
            lab_cur  = lring[(s + 1) & 7];
        }
    }

    // ---- forward score: log(sum_j q_j * Eend_j) + C*ln2 ----
    float v = q * Eend;
#pragma unroll
    for (int m = 16; m >= 1; m >>= 1) v += __shfl_xor(v, m, 32);
    float fwd = __logf(v) + (float)C * 0.69314718055994531f;

    // ---- gold: reduce emission part; trans part identical on all lanes ----
#pragma unroll
    for (int m = 16; m >= 1; m >>= 1) emit_acc += __shfl_xor(emit_acc, m, 32);
    float gold = emit_acc + trans_acc + shT[1 * 32 + prev];  // + trans[END, last]

    if (j == 0) diff_out[b] = fwd - gold;
}

__global__ __launch_bounds__(256) void crf_reduce_kernel(
    const float* __restrict__ diff, float* __restrict__ out)
{
    float v = diff[threadIdx.x] + diff[threadIdx.x + 256];
#pragma unroll
    for (int m = 32; m >= 1; m >>= 1) v += __shfl_xor(v, m, 64);
    __shared__ float sacc[4];
    if ((threadIdx.x & 63) == 0) sacc[threadIdx.x >> 6] = v;
    __syncthreads();
    if (threadIdx.x == 0) out[0] = (sacc[0] + sacc[1]) + (sacc[2] + sacc[3]);
}

extern "C" void kernel_launch(void* const* d_in, const int* in_sizes, int n_in,
                              void* d_out, int out_size, void* d_ws, size_t ws_size,
                              hipStream_t stream)
{
    const float* emission    = (const float*)d_in[0];
    const int*   label_ids   = (const int*)d_in[1];
    const float* transitions = (const float*)d_in[2];
    float* diff = (float*)d_ws;          // 512 floats scratch
    float* out  = (float*)d_out;         // 1 float

    crf_forward_kernel<<<BB / 2, 64, 0, stream>>>(emission, label_ids, transitions, diff);
    crf_reduce_kernel<<<1, 256, 0, stream>>>(diff, out);
}